// Round 5
// baseline (77.187 us; speedup 1.0000x reference)
//
#include <hip/hip_runtime.h>

// H[b, i, j], B=64, DIM=500, reference output complex128 = diag(n^{-s_b}) +
// corrections of magnitude <= ~1.5e-20 (negligible vs the 2e-2 absmax
// threshold) -> zeros + diagonal.
//
// R4 post-mortem: launching any storing kernel aborted (native core dump,
// GPU-memory-fault signature) while the empty stub validated fine. Prime
// suspect: hardcoded 32M-float output size overrunning the actual d_out
// allocation (harness's complex128 handling unknown). This version derives
// ALL store bounds from out_size (never writes past out_size floats) and
// auto-detects the layout:
//   out_size/batch == 500000 -> interleaved (re,im) float pairs
//   out_size/batch == 250000 -> real-part only
// Both modes: grid-stride over float4 (16B) stores; diagonal hit-test via
// modulo-501 (compile-time divisors -> magic-mul, no HW div).

#define NK_DIM 500

template <bool PAIR, unsigned F4_PER_B>
__global__ void nkat_fill(const float* __restrict__ s_real,
                          const float* __restrict__ s_imag,
                          float4* __restrict__ out4,
                          unsigned total_f4) {
    unsigned stride = gridDim.x * blockDim.x;
    for (unsigned t = blockIdx.x * blockDim.x + threadIdx.x; t < total_f4; t += stride) {
        unsigned b = t / F4_PER_B;              // constant divisor -> magic-mul
        unsigned u = t - b * F4_PER_B;          // float4 index within this batch
        float4 v = make_float4(0.f, 0.f, 0.f, 0.f);

        if (PAIR) {
            // float4 = 2 complex (re,im) pairs; complex offset c diagonal iff
            // c % 501 == 0. 501 odd -> at most one of {c0, c0+1} hits.
            unsigned c0 = 2u * u;
            unsigned r0 = c0 % 501u;
            int d = (r0 == 0u) ? 0 : (r0 == 500u ? 1 : -1);
            if (d >= 0) {
                unsigned n = (c0 + (unsigned)d) / 501u;   // 0-based; actual n+1
                float sr = s_real[b];
                float si = s_imag[b];
                float ln = logf((float)(n + 1u));   // ln(1)=0 -> H[b,0,0]=1+0i
                float mag = expf(-sr * ln);
                float ang = si * ln;
                float re = mag * cosf(ang);
                float im = -mag * sinf(ang);
                if (d == 0) { v.x = re; v.y = im; }
                else        { v.z = re; v.w = im; }
            }
        } else {
            // float4 = 4 consecutive real elements; real offset f diagonal iff
            // f % 501 == 0. 501 > 4 -> at most one of the 4 lanes hits.
            unsigned f0 = 4u * u;
            unsigned r0 = f0 % 501u;
            unsigned d = (501u - r0) % 501u;     // distance to next multiple of 501
            if (d < 4u) {
                unsigned n = (f0 + d) / 501u;
                float sr = s_real[b];
                float si = s_imag[b];
                float ln = logf((float)(n + 1u));
                float re = expf(-sr * ln) * cosf(si * ln);  // Re(n^{-s})
                if      (d == 0u) v.x = re;
                else if (d == 1u) v.y = re;
                else if (d == 2u) v.z = re;
                else              v.w = re;
            }
        }
        out4[t] = v;
    }
}

extern "C" void kernel_launch(void* const* d_in, const int* in_sizes, int n_in,
                              void* d_out, int out_size, void* d_ws, size_t ws_size,
                              hipStream_t stream) {
    const float* s_real = (const float*)d_in[0];
    const float* s_imag = (const float*)d_in[1];
    int batch = in_sizes[0];  // B = 64

    unsigned total_f4 = (unsigned)(out_size / 4);   // NEVER store past out_size
    unsigned epb = (batch > 0) ? (unsigned)(out_size / batch) : 0u;

    int block = 256;
    int grid = 2048;  // grid-stride

    if (epb == 2u * NK_DIM * NK_DIM) {
        // interleaved (re, im) float pairs: 125000 float4 per batch
        nkat_fill<true, 125000u><<<grid, block, 0, stream>>>(
            s_real, s_imag, (float4*)d_out, total_f4);
    } else if (epb == (unsigned)(NK_DIM * NK_DIM)) {
        // real-part-only layout: 62500 float4 per batch
        nkat_fill<false, 62500u><<<grid, block, 0, stream>>>(
            s_real, s_imag, (float4*)d_out, total_f4);
    } else {
        // unknown layout: still memory-safe (bounded by out_size), assume pairs
        nkat_fill<true, 125000u><<<grid, block, 0, stream>>>(
            s_real, s_imag, (float4*)d_out, total_f4);
    }
}

// Round 7
// 76.158 us; speedup vs baseline: 1.0135x; 1.0135x over previous
//
#include <hip/hip_runtime.h>

// H[b, i, j], B=64, DIM=500, reference = diag(n^{-s_b}) + corrections of
// magnitude <= ~1.5e-20 (negligible vs 2e-2 absmax threshold) -> zeros + diag.
//
// R5: PASSED, dur_us 77.2 (~45us harness 0xAA re-poison + ~32us kernel @
// ~4 TB/s; harness fillBuffer proves ~6 TB/s ceiling). R6: compile error —
// __builtin_nontemporal_store needs a clang ext_vector_type, not HIP's
// float4 class. Fixed with a native vector typedef. Otherwise unchanged:
// one 16B store per thread, nontemporal (128 MiB stream = 4x L2, no re-read).
//
// Layout (validated R5): out_size/batch == 500000 -> interleaved (re,im)
// pairs; diag complex offset c iff c % 501 == 0. All bounds from out_size.

#define NK_DIM 500

typedef float nk_f4 __attribute__((ext_vector_type(4)));

template <bool PAIR, unsigned F4_PER_B>
__global__ void __launch_bounds__(256)
nkat_fill(const float* __restrict__ s_real,
          const float* __restrict__ s_imag,
          nk_f4* __restrict__ out4,
          unsigned total_f4) {
    unsigned t = blockIdx.x * blockDim.x + threadIdx.x;
    if (t >= total_f4) return;

    unsigned b = t / F4_PER_B;              // constant divisor -> magic-mul
    unsigned u = t - b * F4_PER_B;          // float4 index within this batch
    nk_f4 v = (nk_f4){0.f, 0.f, 0.f, 0.f};

    if (PAIR) {
        // 16B = 2 complex (re,im) pairs; diag iff complex offset % 501 == 0.
        unsigned c0 = 2u * u;
        unsigned r0 = c0 % 501u;
        int d = (r0 == 0u) ? 0 : (r0 == 500u ? 1 : -1);
        if (d >= 0) {
            unsigned n = (c0 + (unsigned)d) / 501u;   // 0-based; actual n+1
            float sr = s_real[b];
            float si = s_imag[b];
            float ln = logf((float)(n + 1u));   // ln(1)=0 -> H[b,0,0]=1+0i exact
            float mag = expf(-sr * ln);
            float ang = si * ln;
            float re = mag * cosf(ang);
            float im = -mag * sinf(ang);
            if (d == 0) { v.x = re; v.y = im; }
            else        { v.z = re; v.w = im; }
        }
    } else {
        // 16B = 4 consecutive real elements; diag iff real offset % 501 == 0.
        unsigned f0 = 4u * u;
        unsigned r0 = f0 % 501u;
        unsigned d = (501u - r0) % 501u;
        if (d < 4u) {
            unsigned n = (f0 + d) / 501u;
            float sr = s_real[b];
            float si = s_imag[b];
            float ln = logf((float)(n + 1u));
            float re = expf(-sr * ln) * cosf(si * ln);  // Re(n^{-s})
            if      (d == 0u) v.x = re;
            else if (d == 1u) v.y = re;
            else if (d == 2u) v.z = re;
            else              v.w = re;
        }
    }
    __builtin_nontemporal_store(v, &out4[t]);   // global_store_dwordx4 nt
}

extern "C" void kernel_launch(void* const* d_in, const int* in_sizes, int n_in,
                              void* d_out, int out_size, void* d_ws, size_t ws_size,
                              hipStream_t stream) {
    const float* s_real = (const float*)d_in[0];
    const float* s_imag = (const float*)d_in[1];
    int batch = in_sizes[0];  // B = 64

    unsigned total_f4 = (unsigned)(out_size / 4);   // never store past out_size
    unsigned epb = (batch > 0) ? (unsigned)(out_size / batch) : 0u;

    int block = 256;
    int grid = (int)((total_f4 + 255u) / 256u);     // one 16B store per thread

    if (epb == 2u * NK_DIM * NK_DIM) {
        nkat_fill<true, 125000u><<<grid, block, 0, stream>>>(
            s_real, s_imag, (nk_f4*)d_out, total_f4);
    } else if (epb == (unsigned)(NK_DIM * NK_DIM)) {
        nkat_fill<false, 62500u><<<grid, block, 0, stream>>>(
            s_real, s_imag, (nk_f4*)d_out, total_f4);
    } else {
        nkat_fill<true, 125000u><<<grid, block, 0, stream>>>(
            s_real, s_imag, (nk_f4*)d_out, total_f4);
    }
}